// Round 2
// baseline (430.863 us; speedup 1.0000x reference)
//
#include <hip/hip_runtime.h>
#include <math.h>

// Problem constants: x[B=32][C=256][HW=3136], omega[256][8], rank q=8, niter=2.
#define HW   3136
#define NB   32      // batch (matrix cols of A: A is C x B)
#define NC   256     // channels (matrix rows of A)
#define NQ   8       // low rank
#define TM   16      // m-tile per block
#define CC   8       // c's per LDS chunk
#define SLABF (CC * NB * TM)   // 4096 floats per slab buffer

#define NS   4       // c-slices for partial-Gram kernel
#define CSL  (NC / NS)         // 64 c's per slice
#define NCH  (CSL / CC)        // 8 chunks per slice
#define GK   784     // per-m partial record: 528 sym-Gram triangle + 32*8 Y

// ---- phase-B LDS layout ----
#define YT_(mi,b,q) Sm[(mi)*265 + (q)*33 + (b)]
#define WT_(mi,b,q) Sm[4240 + (mi)*265 + (q)*33 + (b)]
#define SS_(mi,k)   Sm[8480 + (mi)*65 + (k)]
#define SMEMF 9520

__host__ __device__ constexpr int TRI(int i, int j) { return i*8 - (i*(i+1))/2 + j; } // 8-dim upper tri
__device__ __forceinline__ int tri32(int i, int j) {  // i<=j, 32-dim upper triangle, 528 slots
  return i * 32 - (i * (i - 1)) / 2 + (j - i);
}

// ---- coalesced global->reg->LDS staging (slab layout [cc][b][mi], mi contiguous) ----
__device__ __forceinline__ void stage_load(float4* r, const float* __restrict__ xg,
                                           int c0, int m0, int t) {
#pragma unroll
  for (int i = 0; i < 4; ++i) {
    int id = t + i * 256;                 // 0..1023 float4's per chunk
    int cc = id >> 7, b = (id >> 2) & 31, mq = id & 3;
    r[i] = *reinterpret_cast<const float4*>(
        xg + (size_t)(b * NC + c0 + cc) * HW + m0 + mq * 4);
  }
}
__device__ __forceinline__ void stage_write(const float4* r, float* sl, int t) {
#pragma unroll
  for (int i = 0; i < 4; ++i) {
    int id = t + i * 256;
    int cc = id >> 7, b = (id >> 2) & 31, mq = id & 3;
    *reinterpret_cast<float4*>(sl + cc * (NB * TM) + b * TM + mq * 4) = r[i];
  }
}

// ---- replicated 8x8 Cholesky from SS (upper R; diag slot holds 1/R[i][i]) ----
__device__ __forceinline__ void chol8(const float* __restrict__ Sm, int mi, float* Rl) {
#pragma unroll
  for (int i = 0; i < 8; ++i) {
    float d = SS_(mi, i * 8 + i);
#pragma unroll
    for (int k = 0; k < 8; ++k) {
      if (k < i) { float rk = Rl[TRI(k, i)]; d = fmaf(-rk, rk, d); }
    }
    float rii = sqrtf(fmaxf(d, 1e-30f));
    float inv = 1.0f / rii;
    Rl[TRI(i, i)] = inv;
#pragma unroll
    for (int j = 0; j < 8; ++j) {
      if (j > i) {
        float v = SS_(mi, i * 8 + j);
#pragma unroll
        for (int k = 0; k < 8; ++k) {
          if (k < i) v = fmaf(-Rl[TRI(k, i)], Rl[TRI(k, j)], v);
        }
        Rl[TRI(i, j)] = v * inv;
      }
    }
  }
}

// rows r0,r0+1: dst = src * R^{-1}  (row-wise forward substitution)
__device__ __forceinline__ void trsm2rows(const float* __restrict__ srcB, float* __restrict__ dstB,
                                          int mi, int r0, const float* Rl) {
#pragma unroll
  for (int rr = 0; rr < 2; ++rr) {
    int r = r0 + rr;
    float yv[8], qv[8];
#pragma unroll
    for (int q = 0; q < 8; ++q) yv[q] = srcB[mi * 265 + q * 33 + r];
#pragma unroll
    for (int j = 0; j < 8; ++j) {
      float a = yv[j];
#pragma unroll
      for (int k = 0; k < 8; ++k) {
        if (k < j) a = fmaf(-qv[k], Rl[TRI(k, j)], a);
      }
      qv[j] = a * Rl[TRI(j, j)];
    }
#pragma unroll
    for (int q = 0; q < 8; ++q) dstB[mi * 265 + q * 33 + r] = qv[q];
  }
}

// one CholeskyQR pass in-place on YT (call twice for CholQR2)
__device__ __forceinline__ void cholqr_pass(float* __restrict__ Sm, int mi, int t16, int r0) {
#pragma unroll
  for (int e = 0; e < 4; ++e) {
    int idx = t16 * 4 + e, i = idx >> 3, j = idx & 7;
    float s = 0.f;
#pragma unroll
    for (int b = 0; b < 32; ++b) s = fmaf(YT_(mi, b, i), YT_(mi, b, j), s);
    SS_(mi, idx) = s;
  }
  __syncthreads();
  float Rl[36];
  chol8(Sm, mi, Rl);
  trsm2rows(Sm, Sm, mi, r0, Rl);
  __syncthreads();
}

// ============ Kernel 1a: partial Gram + partial Y0 over one c-slice ============
// Gp record per m: k in [0,784): k<528 -> sym G triangle tri32(i,j); k=528+b*8+q -> Y0[b][q]
// layout: Gp[(s*GK + k)*HW + m]
__global__ __launch_bounds__(256) void tsvd_k1a(const float* __restrict__ x,
                                                const float* __restrict__ omega,
                                                float* __restrict__ Gp) {
  __shared__ float Sm[2 * SLABF];
  const int t = threadIdx.x;
  const int mi = t & 15, t16 = t >> 4;
  const int r0 = 2 * t16, r1 = r0 + 1;
  const int s = blockIdx.x & (NS - 1);
  const int mt = blockIdx.x / NS;
  const int m0 = mt * TM, m = m0 + mi;
  const int c0 = s * CSL;

  float G0[32], G1[32], Y00[8], Y01[8];
#pragma unroll
  for (int b = 0; b < 32; ++b) { G0[b] = 0.f; G1[b] = 0.f; }
#pragma unroll
  for (int q = 0; q < 8; ++q) { Y00[q] = 0.f; Y01[q] = 0.f; }

  float4 st[4];
  stage_load(st, x, c0, m0, t);
  stage_write(st, Sm, t);
  for (int ch = 0; ch < NCH; ++ch) {
    if (ch + 1 < NCH) stage_load(st, x, c0 + (ch + 1) * CC, m0, t);
    __syncthreads();
    const float* cur = Sm + (ch & 1) * SLABF;
#pragma unroll
    for (int cc = 0; cc < CC; ++cc) {
      int c = c0 + ch * CC + cc;
      float w[8];
#pragma unroll
      for (int q = 0; q < 8; ++q) w[q] = omega[c * 8 + q];
      const float* v = cur + cc * (NB * TM) + mi;
      float vr0 = v[r0 * TM], vr1 = v[r1 * TM];
#pragma unroll
      for (int b = 0; b < 32; ++b) {
        float vb = v[b * TM];
        G0[b] = fmaf(vr0, vb, G0[b]);
        G1[b] = fmaf(vr1, vb, G1[b]);
      }
#pragma unroll
      for (int q = 0; q < 8; ++q) {
        Y00[q] = fmaf(vr0, w[q], Y00[q]);
        Y01[q] = fmaf(vr1, w[q], Y01[q]);
      }
    }
    if (ch + 1 < NCH) stage_write(st, Sm + ((ch + 1) & 1) * SLABF, t);
  }

  // write partial triangle rows r0, r1 (single writer per tri slot) + Y rows
  const size_t sb = (size_t)s * GK;
#pragma unroll
  for (int b = 0; b < 32; ++b) {
    if (b >= r0) Gp[(sb + tri32(r0, b)) * HW + m] = G0[b];
    if (b >= r1) Gp[(sb + tri32(r1, b)) * HW + m] = G1[b];
  }
#pragma unroll
  for (int q = 0; q < 8; ++q) {
    Gp[(sb + 528 + r0 * 8 + q) * HW + m] = Y00[q];
    Gp[(sb + 528 + r1 * 8 + q) * HW + m] = Y01[q];
  }
}

// ============ Kernel 1b: reduce partials -> G rows in regs, then CholQR solve -> M ============
__global__ __launch_bounds__(256) void tsvd_k1b(const float* __restrict__ Gp,
                                                float* __restrict__ Mws) {
  __shared__ float Sm[SMEMF];
  const int t = threadIdx.x;
  const int mi = t & 15, t16 = t >> 4;
  const int r0 = 2 * t16, r1 = r0 + 1;
  const int m0 = blockIdx.x * TM, m = m0 + mi;

  float G0[32], G1[32], Y00[8], Y01[8];
#pragma unroll
  for (int b = 0; b < 32; ++b) {
    int k0 = (r0 <= b) ? tri32(r0, b) : tri32(b, r0);
    int k1 = (r1 <= b) ? tri32(r1, b) : tri32(b, r1);
    float a0 = 0.f, a1 = 0.f;
#pragma unroll
    for (int s = 0; s < NS; ++s) {
      a0 += Gp[((size_t)s * GK + k0) * HW + m];
      a1 += Gp[((size_t)s * GK + k1) * HW + m];
    }
    G0[b] = a0; G1[b] = a1;
  }
#pragma unroll
  for (int q = 0; q < 8; ++q) {
    float a0 = 0.f, a1 = 0.f;
#pragma unroll
    for (int s = 0; s < NS; ++s) {
      a0 += Gp[((size_t)s * GK + 528 + r0 * 8 + q) * HW + m];
      a1 += Gp[((size_t)s * GK + 528 + r1 * 8 + q) * HW + m];
    }
    Y00[q] = a0; Y01[q] = a1;
  }

  // ---- phase B (verbatim from validated kernel) ----
#pragma unroll
  for (int q = 0; q < 8; ++q) { YT_(mi, r0, q) = Y00[q]; YT_(mi, r1, q) = Y01[q]; }
  __syncthreads();

#pragma unroll
  for (int it = 0; it < 3; ++it) {
    cholqr_pass(Sm, mi, t16, r0);
    cholqr_pass(Sm, mi, t16, r0);
    if (it < 2) {
      // U = G*Q -> WT
#pragma unroll
      for (int q = 0; q < 8; ++q) {
        float u0 = 0.f, u1 = 0.f;
#pragma unroll
        for (int b = 0; b < 32; ++b) {
          float qb = YT_(mi, b, q);
          u0 = fmaf(G0[b], qb, u0);
          u1 = fmaf(G1[b], qb, u1);
        }
        WT_(mi, r0, q) = u0; WT_(mi, r1, q) = u1;
      }
      __syncthreads();
      // T = Q^T G Q -> SS
#pragma unroll
      for (int e = 0; e < 4; ++e) {
        int idx = t16 * 4 + e, i2 = idx >> 3, j2 = idx & 7;
        float s = 0.f;
#pragma unroll
        for (int b = 0; b < 32; ++b) s = fmaf(YT_(mi, b, i2), WT_(mi, b, j2), s);
        SS_(mi, idx) = s;
      }
      __syncthreads();
      // W = Q R^{-1} -> WT
      {
        float Rl[36];
        chol8(Sm, mi, Rl);
        trsm2rows(Sm, Sm + 4240, mi, r0, Rl);
      }
      __syncthreads();
      // Y_next = G*W -> YT
#pragma unroll
      for (int q = 0; q < 8; ++q) {
        float u0 = 0.f, u1 = 0.f;
#pragma unroll
        for (int b = 0; b < 32; ++b) {
          float wb = WT_(mi, b, q);
          u0 = fmaf(G0[b], wb, u0);
          u1 = fmaf(G1[b], wb, u1);
        }
        YT_(mi, r0, q) = u0; YT_(mi, r1, q) = u1;
      }
      __syncthreads();
    }
  }

  // M = Q2 Q2^T, stored m-contiguous: Mws[(b1*32+b2)*HW + m]
  float q0[8], q1[8];
#pragma unroll
  for (int qq = 0; qq < 8; ++qq) { q0[qq] = YT_(mi, r0, qq); q1[qq] = YT_(mi, r1, qq); }
#pragma unroll
  for (int b2 = 0; b2 < 32; ++b2) {
    float a0 = 0.f, a1 = 0.f;
#pragma unroll
    for (int qq = 0; qq < 8; ++qq) {
      float z = YT_(mi, b2, qq);
      a0 = fmaf(q0[qq], z, a0);
      a1 = fmaf(q1[qq], z, a1);
    }
    Mws[(size_t)(r0 * 32 + b2) * HW + m] = a0;
    Mws[(size_t)(r1 * 32 + b2) * HW + m] = a1;
  }
}

// ============ Kernel 2: y[b][c][m] = sum_b' x[b'][c][m] * M[b'][b][m] ============
// 8 c-slices of 32 channels -> grid 1568 for latency hiding
__global__ __launch_bounds__(256) void tsvd_k2(const float* __restrict__ x,
                                               const float* __restrict__ Mws,
                                               float* __restrict__ y) {
  __shared__ float slab[2 * SLABF];
  const int t = threadIdx.x;
  const int mi = t & 15, t16 = t >> 4;
  const int r0 = 2 * t16, r1 = r0 + 1;
  const int bid = blockIdx.x;
  const int mt = bid % 196, cq = bid / 196;      // 196 m-tiles x 8 c-slices
  const int m0 = mt * TM, m = m0 + mi;
  const int cbase = cq * 32;

  float M0[32], M1[32];
#pragma unroll
  for (int b = 0; b < 32; ++b) {
    M0[b] = Mws[(size_t)(b * 32 + r0) * HW + m];
    M1[b] = Mws[(size_t)(b * 32 + r1) * HW + m];
  }

  float4 st[4];
  stage_load(st, x, cbase, m0, t);
  stage_write(st, slab, t);
  for (int ch = 0; ch < 4; ++ch) {
    if (ch + 1 < 4) stage_load(st, x, cbase + (ch + 1) * CC, m0, t);
    __syncthreads();
    const float* cur = slab + (ch & 1) * SLABF;
#pragma unroll
    for (int cc = 0; cc < CC; ++cc) {
      int c = cbase + ch * CC + cc;
      const float* v = cur + cc * (NB * TM) + mi;
      float a0 = 0.f, a1 = 0.f;
#pragma unroll
      for (int b = 0; b < 32; ++b) {
        float vb = v[b * TM];
        a0 = fmaf(vb, M0[b], a0);
        a1 = fmaf(vb, M1[b], a1);
      }
      y[((size_t)r0 * NC + c) * HW + m] = a0;
      y[((size_t)r1 * NC + c) * HW + m] = a1;
    }
    if (ch + 1 < 4) stage_write(st, slab + ((ch + 1) & 1) * SLABF, t);
  }
}

extern "C" void kernel_launch(void* const* d_in, const int* in_sizes, int n_in,
                              void* d_out, int out_size, void* d_ws, size_t ws_size,
                              hipStream_t stream) {
  const float* x     = (const float*)d_in[0];   // 32*256*3136 fp32
  const float* omega = (const float*)d_in[1];   // 256*8 fp32
  float* y   = (float*)d_out;                   // 32*256*3136 fp32
  float* Mws = (float*)d_ws;                    // 1024*3136*4 = 12.85 MB (proven fit)
  // Partial-Gram scratch lives in d_out: 4*784*3136*4B = 39.3 MB << 103 MB,
  // fully consumed by k1b before k2 overwrites d_out with y.
  float* Gp  = (float*)d_out;

  tsvd_k1a<<<196 * NS, 256, 0, stream>>>(x, omega, Gp);
  tsvd_k1b<<<196, 256, 0, stream>>>(Gp, Mws);
  tsvd_k2<<<196 * 8, 256, 0, stream>>>(x, Mws, y);
}

// Round 4
// 358.355 us; speedup vs baseline: 1.2023x; 1.2023x over previous
//
#include <hip/hip_runtime.h>
#include <math.h>

// Problem: x[B=32][C=256][HW=3136] fp32, omega[256][8]; rank q=8, niter=2.
// y = A Q2 Q2^T per spatial m, via Gram-matrix reformulation (G = A^T A, 32x32).
#define HW   3136
#define NB   32
#define NC   256
#define TM   16              // m's per block in streaming kernels
#define CC   8               // c's per LDS chunk
#define LDP  36              // padded b-stride in transposed slab (bank-spread)
#define SLABC (TM * LDP)     // 576 floats per cc
#define SLABF (CC * SLABC)   // 4608 floats per buffer (2 buffers = 36864 B)

#define NS   4               // c-slices for partial Gram
#define CSL  (NC / NS)       // 64 c per slice
#define NCH  (CSL / CC)      // 8 chunks per slice
#define GK   1280            // per-slice per-m record: 1024 (full G) + 256 (Y)

// ---- k1b (solve) LDS layout: mi in 0..7, odd strides -> bank-spread ----
#define YT_(mi,b,q) Sm[(mi)*265 + (q)*33 + (b)]
#define WT_(mi,b,q) Sm[4240 + (mi)*265 + (q)*33 + (b)]
#define SS_(mi,k)   Sm[8480 + (mi)*65 + (k)]
#define SMEMF 9520

__host__ __device__ constexpr int TRI(int i, int j) { return i*8 - (i*(i+1))/2 + j; }

// ---- 512-thread staging: global (m-coalesced float4) -> transposed slab [cc][m][b] ----
__device__ __forceinline__ void stage_load512(float4* r, const float* __restrict__ xg,
                                              int c0, int m0, int t) {
#pragma unroll
  for (int i = 0; i < 2; ++i) {
    int id = t + i * 512;                 // 0..1023 float4 per chunk
    int cc = id >> 7, b = (id >> 2) & 31, mq = id & 3;
    r[i] = *reinterpret_cast<const float4*>(
        xg + (size_t)(b * NC + c0 + cc) * HW + m0 + mq * 4);
  }
}
__device__ __forceinline__ void stage_write_t(const float4* r, float* sl, int t) {
#pragma unroll
  for (int i = 0; i < 2; ++i) {
    int id = t + i * 512;
    int cc = id >> 7, b = (id >> 2) & 31, mq = id & 3;
    float* p = sl + cc * SLABC + (mq * 4) * LDP + b;   // 4 scalar writes, 2-way max
    p[0 * LDP] = r[i].x;
    p[1 * LDP] = r[i].y;
    p[2 * LDP] = r[i].z;
    p[3 * LDP] = r[i].w;
  }
}

// ---- replicated 8x8 Cholesky from SS (upper R; diag slot holds 1/R[i][i]) ----
__device__ __forceinline__ void chol8(const float* __restrict__ Sm, int mi, float* Rl) {
#pragma unroll
  for (int i = 0; i < 8; ++i) {
    float d = SS_(mi, i * 8 + i);
#pragma unroll
    for (int k = 0; k < 8; ++k) {
      if (k < i) { float rk = Rl[TRI(k, i)]; d = fmaf(-rk, rk, d); }
    }
    float rii = sqrtf(fmaxf(d, 1e-30f));
    float inv = 1.0f / rii;
    Rl[TRI(i, i)] = inv;
#pragma unroll
    for (int j = 0; j < 8; ++j) {
      if (j > i) {
        float v = SS_(mi, i * 8 + j);
#pragma unroll
        for (int k = 0; k < 8; ++k) {
          if (k < i) v = fmaf(-Rl[TRI(k, i)], Rl[TRI(k, j)], v);
        }
        Rl[TRI(i, j)] = v * inv;
      }
    }
  }
}

// row r: dst_row = src_row * R^{-1} (forward substitution through upper R)
__device__ __forceinline__ void trsm1row(const float* __restrict__ srcB, float* __restrict__ dstB,
                                         int mi, int r, const float* Rl) {
  float yv[8], qv[8];
#pragma unroll
  for (int q = 0; q < 8; ++q) yv[q] = srcB[mi * 265 + q * 33 + r];
#pragma unroll
  for (int j = 0; j < 8; ++j) {
    float a = yv[j];
#pragma unroll
    for (int k = 0; k < 8; ++k) {
      if (k < j) a = fmaf(-qv[k], Rl[TRI(k, j)], a);
    }
    qv[j] = a * Rl[TRI(j, j)];
  }
#pragma unroll
  for (int q = 0; q < 8; ++q) dstB[mi * 265 + q * 33 + r] = qv[q];
}

// one CholeskyQR pass in-place on YT (32 threads per m; thread owns row r)
__device__ __forceinline__ void cholqr32(float* __restrict__ Sm, int mi, int r) {
#pragma unroll
  for (int e = 0; e < 2; ++e) {
    int idx = r + e * 32, i = idx >> 3, j = idx & 7;
    float s = 0.f;
#pragma unroll
    for (int b = 0; b < 32; ++b) s = fmaf(YT_(mi, b, i), YT_(mi, b, j), s);
    SS_(mi, idx) = s;
  }
  __syncthreads();
  float Rl[36];
  chol8(Sm, mi, Rl);
  trsm1row(Sm, Sm, mi, r, Rl);
  __syncthreads();
}

// ============ K1a: partial Gram rows + partial Y0 over one c-slice ============
// Gp[(s*GK + k)*HW + m]; k<1024: G[r][b] full rows; k=1024+r*8+q: Y0[r][q]
__global__ __launch_bounds__(512, 4) void tsvd_k1a(const float* __restrict__ x,
                                                   const float* __restrict__ omega,
                                                   float* __restrict__ Gp) {
  __shared__ float Sm[2 * SLABF];
  const int t = threadIdx.x;
  const int mi = t & 15, r = t >> 4;            // r in 0..31: owned G row
  const int s = blockIdx.x & (NS - 1);
  const int mt = blockIdx.x / NS;
  const int m0 = mt * TM, m = m0 + mi;
  const int c0 = s * CSL;

  float G[32], Y[8];
#pragma unroll
  for (int b = 0; b < 32; ++b) G[b] = 0.f;
#pragma unroll
  for (int q = 0; q < 8; ++q) Y[q] = 0.f;

  float4 st[2];
  stage_load512(st, x, c0, m0, t);
  stage_write_t(st, Sm, t);
  for (int ch = 0; ch < NCH; ++ch) {
    if (ch + 1 < NCH) stage_load512(st, x, c0 + (ch + 1) * CC, m0, t);
    __syncthreads();
    const float* cur = Sm + (ch & 1) * SLABF;
#pragma unroll
    for (int cc = 0; cc < CC; ++cc) {
      const int c = c0 + ch * CC + cc;
      const float* v = cur + cc * SLABC + mi * LDP;
      const float ar = v[r];                    // own-row scalar (2-way banks)
#pragma unroll
      for (int k = 0; k < 8; ++k) {             // 8x ds_read_b128, broadcast
        float4 vb = *reinterpret_cast<const float4*>(v + 4 * k);
        G[4 * k + 0] = fmaf(ar, vb.x, G[4 * k + 0]);
        G[4 * k + 1] = fmaf(ar, vb.y, G[4 * k + 1]);
        G[4 * k + 2] = fmaf(ar, vb.z, G[4 * k + 2]);
        G[4 * k + 3] = fmaf(ar, vb.w, G[4 * k + 3]);
      }
#pragma unroll
      for (int q = 0; q < 8; ++q) Y[q] = fmaf(ar, omega[c * 8 + q], Y[q]);
    }
    if (ch + 1 < NCH) stage_write_t(st, Sm + ((ch + 1) & 1) * SLABF, t);
  }

  const size_t sb = (size_t)s * GK;
#pragma unroll
  for (int b = 0; b < 32; ++b)
    Gp[(sb + r * 32 + b) * HW + m] = G[b];      // 64B-coalesced per b
#pragma unroll
  for (int q = 0; q < 8; ++q)
    Gp[(sb + 1024 + r * 8 + q) * HW + m] = Y[q];
}

// ============ K1b: reduce slices -> G row in regs; CholQR2 chain -> M = Q2 Q2^T ============
__global__ __launch_bounds__(256, 2) void tsvd_k1b(const float* __restrict__ Gp,
                                                   float* __restrict__ Mws) {
  __shared__ float Sm[SMEMF];
  const int t = threadIdx.x;
  const int r = t & 31, mi = t >> 5;            // 8 m per block, thread owns row r
  const int m0 = blockIdx.x * 8, m = m0 + mi;

  float G0[32], Y0[8];
#pragma unroll
  for (int b = 0; b < 32; ++b) {
    float a = 0.f;
#pragma unroll
    for (int s = 0; s < NS; ++s) a += Gp[((size_t)s * GK + r * 32 + b) * HW + m];
    G0[b] = a;
  }
#pragma unroll
  for (int q = 0; q < 8; ++q) {
    float a = 0.f;
#pragma unroll
    for (int s = 0; s < NS; ++s) a += Gp[((size_t)s * GK + 1024 + r * 8 + q) * HW + m];
    Y0[q] = a;
  }

#pragma unroll
  for (int q = 0; q < 8; ++q) YT_(mi, r, q) = Y0[q];
  __syncthreads();

#pragma unroll
  for (int it = 0; it < 3; ++it) {
    cholqr32(Sm, mi, r);        // CholQR2: orthonormal basis of span(Y)
    cholqr32(Sm, mi, r);
    if (it < 2) {
      // U = G*Q -> WT
      float u[8];
#pragma unroll
      for (int q = 0; q < 8; ++q) {
        float a = 0.f;
#pragma unroll
        for (int b = 0; b < 32; ++b) a = fmaf(G0[b], YT_(mi, b, q), a);
        u[q] = a;
      }
#pragma unroll
      for (int q = 0; q < 8; ++q) WT_(mi, r, q) = u[q];
      __syncthreads();
      // T = Q^T G Q -> SS
#pragma unroll
      for (int e = 0; e < 2; ++e) {
        int idx = r + e * 32, i2 = idx >> 3, j2 = idx & 7;
        float a = 0.f;
#pragma unroll
        for (int b = 0; b < 32; ++b) a = fmaf(YT_(mi, b, i2), WT_(mi, b, j2), a);
        SS_(mi, idx) = a;
      }
      __syncthreads();
      // W = Q R^{-1} -> WT   (implicit qr(A*Q))
      {
        float Rl[36];
        chol8(Sm, mi, Rl);
        trsm1row(Sm, Sm + 4240, mi, r, Rl);
      }
      __syncthreads();
      // Y_next = G*W -> YT
#pragma unroll
      for (int q = 0; q < 8; ++q) {
        float a = 0.f;
#pragma unroll
        for (int b = 0; b < 32; ++b) a = fmaf(G0[b], WT_(mi, b, q), a);
        u[q] = a;
      }
#pragma unroll
      for (int q = 0; q < 8; ++q) YT_(mi, r, q) = u[q];
      __syncthreads();
    }
  }

  // M = Q2 Q2^T (symmetric), m-contiguous: Mws[(r*32+b2)*HW + m]
  float q0[8];
#pragma unroll
  for (int q = 0; q < 8; ++q) q0[q] = YT_(mi, r, q);
#pragma unroll
  for (int b2 = 0; b2 < 32; ++b2) {
    float a = 0.f;
#pragma unroll
    for (int q = 0; q < 8; ++q) a = fmaf(q0[q], YT_(mi, b2, q), a);
    Mws[(size_t)(r * 32 + b2) * HW + m] = a;
  }
}

// ============ K2: y[r][c][m] = sum_b x[b][c][m] * M[b][r][m] ============
__global__ __launch_bounds__(512, 4) void tsvd_k2(const float* __restrict__ x,
                                                  const float* __restrict__ Mws,
                                                  float* __restrict__ y) {
  __shared__ float Sm[2 * SLABF];
  const int t = threadIdx.x;
  const int mi = t & 15, r = t >> 4;            // r: owned output batch row
  const int bid = blockIdx.x;
  const int mt = bid % 196, cq = bid / 196;     // 196 m-tiles x 8 c-slices
  const int m0 = mt * TM, m = m0 + mi;
  const int cbase = cq * 32;

  float Mc[32];                                  // column r of symmetric M
#pragma unroll
  for (int b = 0; b < 32; ++b)
    Mc[b] = Mws[(size_t)(b * 32 + r) * HW + m];  // 64B-coalesced per b

  float4 st[2];
  stage_load512(st, x, cbase, m0, t);
  stage_write_t(st, Sm, t);
  for (int ch = 0; ch < 4; ++ch) {
    if (ch + 1 < 4) stage_load512(st, x, cbase + (ch + 1) * CC, m0, t);
    __syncthreads();
    const float* cur = Sm + (ch & 1) * SLABF;
#pragma unroll
    for (int cc = 0; cc < CC; ++cc) {
      const int c = cbase + ch * CC + cc;
      const float* v = cur + cc * SLABC + mi * LDP;
      float a = 0.f;
#pragma unroll
      for (int k = 0; k < 8; ++k) {
        float4 vb = *reinterpret_cast<const float4*>(v + 4 * k);
        a = fmaf(vb.x, Mc[4 * k + 0], a);
        a = fmaf(vb.y, Mc[4 * k + 1], a);
        a = fmaf(vb.z, Mc[4 * k + 2], a);
        a = fmaf(vb.w, Mc[4 * k + 3], a);
      }
      y[((size_t)r * NC + c) * HW + m] = a;      // 64B-coalesced per (r,c)
    }
    if (ch + 1 < 4) stage_write_t(st, Sm + ((ch + 1) & 1) * SLABF, t);
  }
}

extern "C" void kernel_launch(void* const* d_in, const int* in_sizes, int n_in,
                              void* d_out, int out_size, void* d_ws, size_t ws_size,
                              hipStream_t stream) {
  const float* x     = (const float*)d_in[0];   // 32*256*3136 fp32
  const float* omega = (const float*)d_in[1];   // 256*8 fp32
  float* y   = (float*)d_out;                   // 32*256*3136 fp32
  float* Mws = (float*)d_ws;                    // 1024*3136*4 = 12.85 MB
  // Partial Gram scratch in d_out: 4*1280*3136*4B = 64.2 MB < 102.8 MB;
  // consumed by k1b, then k2 overwrites all of d_out with y.
  float* Gp  = (float*)d_out;

  tsvd_k1a<<<196 * NS, 512, 0, stream>>>(x, omega, Gp);
  tsvd_k1b<<<HW / 8, 256, 0, stream>>>(Gp, Mws);
  tsvd_k2<<<196 * 8, 512, 0, stream>>>(x, Mws, y);
}

// Round 5
// 316.344 us; speedup vs baseline: 1.3620x; 1.1328x over previous
//
#include <hip/hip_runtime.h>
#include <math.h>

// Problem: x[B=32][C=256][HW=3136] fp32, omega[256][8]; rank q=8, niter=2.
// y = A Q2 Q2^T per spatial m, via Gram-matrix reformulation (G = A^T A, 32x32).
#define HW   3136
#define NB   32
#define NC   256
#define TM   16              // m's per block in streaming kernels
#define CC   8               // c's per LDS chunk
#define LDP  36              // padded b-stride in transposed slab (bank-spread)
#define SLABC (TM * LDP)     // 576 floats per cc
#define SLABF (CC * SLABC)   // 4608 floats per buffer (2 buffers = 36864 B)

#define NS   4               // c-slices for partial Gram
#define CSL  (NC / NS)       // 64 c per slice
#define NCH  (CSL / CC)      // 8 chunks per slice
#define GK   1280            // record floats per (slice,m): 1024 G + 256 Y
// RECORD-MAJOR layout (round-5 change): Gp[(s*HW + m)*GK + k]
//   G[r][b] at k = r*32 + b   (8 dense float4 per row)
//   Y[r][q] at k = 1024 + r*8 + q  (2 dense float4 per row)
// M record-major: Mws[m*1024 + r*32 + b]  (M symmetric -> row r == column r)

// ---- k1b (solve) LDS layout: mi in 0..7, odd strides -> bank-spread ----
#define YT_(mi,b,q) Sm[(mi)*265 + (q)*33 + (b)]
#define WT_(mi,b,q) Sm[4240 + (mi)*265 + (q)*33 + (b)]
#define SS_(mi,k)   Sm[8480 + (mi)*65 + (k)]
#define SMEMF 9520

__host__ __device__ constexpr int TRI(int i, int j) { return i*8 - (i*(i+1))/2 + j; }

// ---- 512-thread staging: global (m-coalesced float4) -> transposed slab [cc][m][b] ----
__device__ __forceinline__ void stage_load512(float4* r, const float* __restrict__ xg,
                                              int c0, int m0, int t) {
#pragma unroll
  for (int i = 0; i < 2; ++i) {
    int id = t + i * 512;                 // 0..1023 float4 per chunk
    int cc = id >> 7, b = (id >> 2) & 31, mq = id & 3;
    r[i] = *reinterpret_cast<const float4*>(
        xg + (size_t)(b * NC + c0 + cc) * HW + m0 + mq * 4);
  }
}
__device__ __forceinline__ void stage_write_t(const float4* r, float* sl, int t) {
#pragma unroll
  for (int i = 0; i < 2; ++i) {
    int id = t + i * 512;
    int cc = id >> 7, b = (id >> 2) & 31, mq = id & 3;
    float* p = sl + cc * SLABC + (mq * 4) * LDP + b;   // 4 scalar writes, 2-way max
    p[0 * LDP] = r[i].x;
    p[1 * LDP] = r[i].y;
    p[2 * LDP] = r[i].z;
    p[3 * LDP] = r[i].w;
  }
}

// ---- replicated 8x8 Cholesky from SS (upper R; diag slot holds 1/R[i][i]) ----
__device__ __forceinline__ void chol8(const float* __restrict__ Sm, int mi, float* Rl) {
#pragma unroll
  for (int i = 0; i < 8; ++i) {
    float d = SS_(mi, i * 8 + i);
#pragma unroll
    for (int k = 0; k < 8; ++k) {
      if (k < i) { float rk = Rl[TRI(k, i)]; d = fmaf(-rk, rk, d); }
    }
    float rii = sqrtf(fmaxf(d, 1e-30f));
    float inv = 1.0f / rii;
    Rl[TRI(i, i)] = inv;
#pragma unroll
    for (int j = 0; j < 8; ++j) {
      if (j > i) {
        float v = SS_(mi, i * 8 + j);
#pragma unroll
        for (int k = 0; k < 8; ++k) {
          if (k < i) v = fmaf(-Rl[TRI(k, i)], Rl[TRI(k, j)], v);
        }
        Rl[TRI(i, j)] = v * inv;
      }
    }
  }
}

// row r: dst_row = src_row * R^{-1} (forward substitution through upper R)
__device__ __forceinline__ void trsm1row(const float* __restrict__ srcB, float* __restrict__ dstB,
                                         int mi, int r, const float* Rl) {
  float yv[8], qv[8];
#pragma unroll
  for (int q = 0; q < 8; ++q) yv[q] = srcB[mi * 265 + q * 33 + r];
#pragma unroll
  for (int j = 0; j < 8; ++j) {
    float a = yv[j];
#pragma unroll
    for (int k = 0; k < 8; ++k) {
      if (k < j) a = fmaf(-qv[k], Rl[TRI(k, j)], a);
    }
    qv[j] = a * Rl[TRI(j, j)];
  }
#pragma unroll
  for (int q = 0; q < 8; ++q) dstB[mi * 265 + q * 33 + r] = qv[q];
}

// one CholeskyQR pass in-place on YT (32 threads per m; thread owns row r)
__device__ __forceinline__ void cholqr32(float* __restrict__ Sm, int mi, int r) {
#pragma unroll
  for (int e = 0; e < 2; ++e) {
    int idx = r + e * 32, i = idx >> 3, j = idx & 7;
    float s = 0.f;
#pragma unroll
    for (int b = 0; b < 32; ++b) s = fmaf(YT_(mi, b, i), YT_(mi, b, j), s);
    SS_(mi, idx) = s;
  }
  __syncthreads();
  float Rl[36];
  chol8(Sm, mi, Rl);
  trsm1row(Sm, Sm, mi, r, Rl);
  __syncthreads();
}

// ============ K1a: partial Gram rows + partial Y0 over one c-slice ============
__global__ __launch_bounds__(512, 4) void tsvd_k1a(const float* __restrict__ x,
                                                   const float* __restrict__ omega,
                                                   float* __restrict__ Gp) {
  __shared__ float Sm[2 * SLABF];
  const int t = threadIdx.x;
  const int mi = t & 15, r = t >> 4;            // r in 0..31: owned G row
  const int s = blockIdx.x & (NS - 1);
  const int mt = blockIdx.x / NS;
  const int m0 = mt * TM, m = m0 + mi;
  const int c0 = s * CSL;

  float G[32], Y[8];
#pragma unroll
  for (int b = 0; b < 32; ++b) G[b] = 0.f;
#pragma unroll
  for (int q = 0; q < 8; ++q) Y[q] = 0.f;

  float4 st[2];
  stage_load512(st, x, c0, m0, t);
  stage_write_t(st, Sm, t);
  for (int ch = 0; ch < NCH; ++ch) {
    if (ch + 1 < NCH) stage_load512(st, x, c0 + (ch + 1) * CC, m0, t);
    __syncthreads();
    const float* cur = Sm + (ch & 1) * SLABF;
#pragma unroll
    for (int cc = 0; cc < CC; ++cc) {
      const int c = c0 + ch * CC + cc;
      const float* v = cur + cc * SLABC + mi * LDP;
      const float ar = v[r];                    // own-row scalar (2-way banks)
#pragma unroll
      for (int k = 0; k < 8; ++k) {             // 8x ds_read_b128, broadcast
        float4 vb = *reinterpret_cast<const float4*>(v + 4 * k);
        G[4 * k + 0] = fmaf(ar, vb.x, G[4 * k + 0]);
        G[4 * k + 1] = fmaf(ar, vb.y, G[4 * k + 1]);
        G[4 * k + 2] = fmaf(ar, vb.z, G[4 * k + 2]);
        G[4 * k + 3] = fmaf(ar, vb.w, G[4 * k + 3]);
      }
#pragma unroll
      for (int q = 0; q < 8; ++q) Y[q] = fmaf(ar, omega[c * 8 + q], Y[q]);
    }
    if (ch + 1 < NCH) stage_write_t(st, Sm + ((ch + 1) & 1) * SLABF, t);
  }

  // record-major store: 8 float4 (G row) + 2 float4 (Y row), all dense
  float4* rec = reinterpret_cast<float4*>(Gp + ((size_t)s * HW + m) * GK);
#pragma unroll
  for (int k = 0; k < 8; ++k)
    rec[r * 8 + k] = make_float4(G[4 * k + 0], G[4 * k + 1], G[4 * k + 2], G[4 * k + 3]);
  rec[256 + r * 2 + 0] = make_float4(Y[0], Y[1], Y[2], Y[3]);
  rec[256 + r * 2 + 1] = make_float4(Y[4], Y[5], Y[6], Y[7]);
}

// ============ K1b: reduce slices (dense float4) -> CholQR2 chain -> M = Q2 Q2^T ============
__global__ __launch_bounds__(256) void tsvd_k1b(const float* __restrict__ Gp,
                                                float* __restrict__ Mws) {
  __shared__ float Sm[SMEMF];
  const int t = threadIdx.x;
  const int r = t & 31, mi = t >> 5;            // 8 m per block, thread owns row r
  const int m0 = blockIdx.x * 8, m = m0 + mi;

  float G0[32], Y0[8];
#pragma unroll
  for (int b = 0; b < 32; ++b) G0[b] = 0.f;
#pragma unroll
  for (int q = 0; q < 8; ++q) Y0[q] = 0.f;
#pragma unroll
  for (int s = 0; s < NS; ++s) {
    const float4* rec = reinterpret_cast<const float4*>(Gp + ((size_t)s * HW + m) * GK);
#pragma unroll
    for (int k = 0; k < 8; ++k) {               // 8 dense global_load_dwordx4
      float4 v = rec[r * 8 + k];
      G0[4 * k + 0] += v.x;
      G0[4 * k + 1] += v.y;
      G0[4 * k + 2] += v.z;
      G0[4 * k + 3] += v.w;
    }
    float4 y0 = rec[256 + r * 2 + 0];
    float4 y1 = rec[256 + r * 2 + 1];
    Y0[0] += y0.x; Y0[1] += y0.y; Y0[2] += y0.z; Y0[3] += y0.w;
    Y0[4] += y1.x; Y0[5] += y1.y; Y0[6] += y1.z; Y0[7] += y1.w;
  }

#pragma unroll
  for (int q = 0; q < 8; ++q) YT_(mi, r, q) = Y0[q];
  __syncthreads();

#pragma unroll
  for (int it = 0; it < 3; ++it) {
    cholqr32(Sm, mi, r);        // CholQR2: orthonormal basis of span(Y)
    cholqr32(Sm, mi, r);
    if (it < 2) {
      // U = G*Q -> WT
      float u[8];
#pragma unroll
      for (int q = 0; q < 8; ++q) {
        float a = 0.f;
#pragma unroll
        for (int b = 0; b < 32; ++b) a = fmaf(G0[b], YT_(mi, b, q), a);
        u[q] = a;
      }
#pragma unroll
      for (int q = 0; q < 8; ++q) WT_(mi, r, q) = u[q];
      __syncthreads();
      // T = Q^T G Q -> SS
#pragma unroll
      for (int e = 0; e < 2; ++e) {
        int idx = r + e * 32, i2 = idx >> 3, j2 = idx & 7;
        float a = 0.f;
#pragma unroll
        for (int b = 0; b < 32; ++b) a = fmaf(YT_(mi, b, i2), WT_(mi, b, j2), a);
        SS_(mi, idx) = a;
      }
      __syncthreads();
      // W = Q R^{-1} -> WT   (implicit qr(A*Q))
      {
        float Rl[36];
        chol8(Sm, mi, Rl);
        trsm1row(Sm, Sm + 4240, mi, r, Rl);
      }
      __syncthreads();
      // Y_next = G*W -> YT
#pragma unroll
      for (int q = 0; q < 8; ++q) {
        float a = 0.f;
#pragma unroll
        for (int b = 0; b < 32; ++b) a = fmaf(G0[b], WT_(mi, b, q), a);
        u[q] = a;
      }
#pragma unroll
      for (int q = 0; q < 8; ++q) YT_(mi, r, q) = u[q];
      __syncthreads();
    }
  }

  // M row r (= column r, symmetric), record-major: Mws[m*1024 + r*32 + b]
  float q0[8];
#pragma unroll
  for (int q = 0; q < 8; ++q) q0[q] = YT_(mi, r, q);
  float4* mrec = reinterpret_cast<float4*>(Mws + (size_t)m * 1024);
#pragma unroll
  for (int bq = 0; bq < 8; ++bq) {
    float a[4];
#pragma unroll
    for (int e = 0; e < 4; ++e) {
      int b2 = bq * 4 + e;
      float acc = 0.f;
#pragma unroll
      for (int q = 0; q < 8; ++q) acc = fmaf(q0[q], YT_(mi, b2, q), acc);
      a[e] = acc;
    }
    mrec[r * 8 + bq] = make_float4(a[0], a[1], a[2], a[3]);
  }
}

// ============ K2: y[r][c][m] = sum_b x[b][c][m] * M[r][b at m] ============
__global__ __launch_bounds__(512, 4) void tsvd_k2(const float* __restrict__ x,
                                                  const float* __restrict__ Mws,
                                                  float* __restrict__ y) {
  __shared__ float Sm[2 * SLABF];
  const int t = threadIdx.x;
  const int mi = t & 15, r = t >> 4;            // r: owned output batch row
  const int bid = blockIdx.x;
  const int mt = bid % 196, cq = bid / 196;     // 196 m-tiles x 8 c-slices
  const int m0 = mt * TM, m = m0 + mi;
  const int cbase = cq * 32;

  float Mc[32];                                  // row r of symmetric M (dense float4)
  {
    const float4* mrec = reinterpret_cast<const float4*>(Mws + (size_t)m * 1024);
#pragma unroll
    for (int k = 0; k < 8; ++k) {
      float4 v = mrec[r * 8 + k];
      Mc[4 * k + 0] = v.x; Mc[4 * k + 1] = v.y; Mc[4 * k + 2] = v.z; Mc[4 * k + 3] = v.w;
    }
  }

  float4 st[2];
  stage_load512(st, x, cbase, m0, t);
  stage_write_t(st, Sm, t);
  for (int ch = 0; ch < 4; ++ch) {
    if (ch + 1 < 4) stage_load512(st, x, cbase + (ch + 1) * CC, m0, t);
    __syncthreads();
    const float* cur = Sm + (ch & 1) * SLABF;
#pragma unroll
    for (int cc = 0; cc < CC; ++cc) {
      const int c = cbase + ch * CC + cc;
      const float* v = cur + cc * SLABC + mi * LDP;
      float a = 0.f;
#pragma unroll
      for (int k = 0; k < 8; ++k) {
        float4 vb = *reinterpret_cast<const float4*>(v + 4 * k);
        a = fmaf(vb.x, Mc[4 * k + 0], a);
        a = fmaf(vb.y, Mc[4 * k + 1], a);
        a = fmaf(vb.z, Mc[4 * k + 2], a);
        a = fmaf(vb.w, Mc[4 * k + 3], a);
      }
      y[((size_t)r * NC + c) * HW + m] = a;      // 64B-coalesced per (r,c)
    }
    if (ch + 1 < 4) stage_write_t(st, Sm + ((ch + 1) & 1) * SLABF, t);
  }
}

extern "C" void kernel_launch(void* const* d_in, const int* in_sizes, int n_in,
                              void* d_out, int out_size, void* d_ws, size_t ws_size,
                              hipStream_t stream) {
  const float* x     = (const float*)d_in[0];   // 32*256*3136 fp32
  const float* omega = (const float*)d_in[1];   // 256*8 fp32
  float* y   = (float*)d_out;                   // 32*256*3136 fp32
  float* Mws = (float*)d_ws;                    // 3136*1024*4 = 12.85 MB
  // Partial Gram scratch in d_out: 4*3136*1280*4B = 64.2 MB < 102.8 MB;
  // consumed by k1b, then k2 overwrites all of d_out with y.
  float* Gp  = (float*)d_out;

  tsvd_k1a<<<196 * NS, 512, 0, stream>>>(x, omega, Gp);
  tsvd_k1b<<<HW / 8, 256, 0, stream>>>(Gp, Mws);
  tsvd_k2<<<196 * 8, 512, 0, stream>>>(x, Mws, y);
}

// Round 6
// 307.929 us; speedup vs baseline: 1.3992x; 1.0273x over previous
//
#include <hip/hip_runtime.h>
#include <math.h>

// Problem: x[B=32][C=256][HW=3136] fp32, omega[256][8]; rank q=8, niter=2.
// y = A Q2 Q2^T per spatial m, via Gram reformulation (G = A^T A, 32x32).
// Pipeline: k1a (partial G,Y per c-slice) -> k1b (reduce + CholQR2 chain -> Q2)
//           -> k2 (P = A Q2, y = P Q2^T).
#define HW   3136
#define NB   32
#define NC   256
#define TM   16              // m's per block in streaming kernels
#define CC   8               // c's per LDS chunk
#define LDP  36              // padded b-stride in transposed slab
#define SLABC (TM * LDP)     // 576 floats per cc
#define SLABF (CC * SLABC)   // 4608 floats per buffer

#define NS   4               // c-slices for partial Gram
#define CSL  (NC / NS)       // 64 c per slice
#define NCH  (CSL / CC)      // 8 chunks per slice
#define GK   1280            // record floats per (slice,m): 1024 G + 256 Y
#define PST  68              // k2: P lds stride per m (17 granules -> spread)

// ---- k1b (solve) LDS layout: mi in 0..7, odd strides -> bank-spread ----
#define YT_(mi,b,q) Sm[(mi)*265 + (q)*33 + (b)]
#define WT_(mi,b,q) Sm[4240 + (mi)*265 + (q)*33 + (b)]
#define SS_(mi,k)   Sm[8480 + (mi)*65 + (k)]
#define SMEMF 9520

__host__ __device__ constexpr int TRI(int i, int j) { return i*8 - (i*(i+1))/2 + j; }

// ---- 512-thread staging: global (m-coalesced float4) -> transposed slab [cc][m][b] ----
__device__ __forceinline__ void stage_load512(float4* r, const float* __restrict__ xg,
                                              int c0, int m0, int t) {
#pragma unroll
  for (int i = 0; i < 2; ++i) {
    int id = t + i * 512;                 // 0..1023 float4 per chunk
    int cc = id >> 7, b = (id >> 2) & 31, mq = id & 3;
    r[i] = *reinterpret_cast<const float4*>(
        xg + (size_t)(b * NC + c0 + cc) * HW + m0 + mq * 4);
  }
}
__device__ __forceinline__ void stage_write_t(const float4* r, float* sl, int t) {
#pragma unroll
  for (int i = 0; i < 2; ++i) {
    int id = t + i * 512;
    int cc = id >> 7, b = (id >> 2) & 31, mq = id & 3;
    float* p = sl + cc * SLABC + (mq * 4) * LDP + b;
    p[0 * LDP] = r[i].x;
    p[1 * LDP] = r[i].y;
    p[2 * LDP] = r[i].z;
    p[3 * LDP] = r[i].w;
  }
}

// ---- replicated 8x8 Cholesky from SS (upper R; diag slot holds 1/R[i][i]) ----
__device__ __forceinline__ void chol8(const float* __restrict__ Sm, int mi, float* Rl) {
#pragma unroll
  for (int i = 0; i < 8; ++i) {
    float d = SS_(mi, i * 8 + i);
#pragma unroll
    for (int k = 0; k < 8; ++k) {
      if (k < i) { float rk = Rl[TRI(k, i)]; d = fmaf(-rk, rk, d); }
    }
    float rii = sqrtf(fmaxf(d, 1e-30f));
    float inv = 1.0f / rii;
    Rl[TRI(i, i)] = inv;
#pragma unroll
    for (int j = 0; j < 8; ++j) {
      if (j > i) {
        float v = SS_(mi, i * 8 + j);
#pragma unroll
        for (int k = 0; k < 8; ++k) {
          if (k < i) v = fmaf(-Rl[TRI(k, i)], Rl[TRI(k, j)], v);
        }
        Rl[TRI(i, j)] = v * inv;
      }
    }
  }
}

// row r: dst_row = src_row * R^{-1} (forward substitution through upper R)
__device__ __forceinline__ void trsm1row(const float* __restrict__ srcB, float* __restrict__ dstB,
                                         int mi, int r, const float* Rl) {
  float yv[8], qv[8];
#pragma unroll
  for (int q = 0; q < 8; ++q) yv[q] = srcB[mi * 265 + q * 33 + r];
#pragma unroll
  for (int j = 0; j < 8; ++j) {
    float a = yv[j];
#pragma unroll
    for (int k = 0; k < 8; ++k) {
      if (k < j) a = fmaf(-qv[k], Rl[TRI(k, j)], a);
    }
    qv[j] = a * Rl[TRI(j, j)];
  }
#pragma unroll
  for (int q = 0; q < 8; ++q) dstB[mi * 265 + q * 33 + r] = qv[q];
}

// one CholeskyQR pass in-place on YT (32 threads per m; thread owns row r)
__device__ __forceinline__ void cholqr32(float* __restrict__ Sm, int mi, int r) {
#pragma unroll
  for (int e = 0; e < 2; ++e) {
    int idx = r + e * 32, i = idx >> 3, j = idx & 7;
    float s = 0.f;
#pragma unroll
    for (int b = 0; b < 32; ++b) s = fmaf(YT_(mi, b, i), YT_(mi, b, j), s);
    SS_(mi, idx) = s;
  }
  __syncthreads();
  float Rl[36];
  chol8(Sm, mi, Rl);
  trsm1row(Sm, Sm, mi, r, Rl);
  __syncthreads();
}

// ============ K1a: partial Gram (8r x 4b register tile) + partial Y0 ============
// thread = (mi, rg in 0..3 -> 8 rows, bj in 0..7 -> 4 cols, q = bj for Y)
__global__ __launch_bounds__(512, 4) void tsvd_k1a(const float* __restrict__ x,
                                                   const float* __restrict__ omega,
                                                   float* __restrict__ Gp) {
  __shared__ float Sm[2 * SLABF];
  const int t = threadIdx.x;
  const int mi = t & 15, g = t >> 4;
  const int rg = g >> 3, bj = g & 7;
  const int r0 = rg * 8, b0 = bj * 4;
  const int s = blockIdx.x & (NS - 1);
  const int mt = blockIdx.x / NS;
  const int m0 = mt * TM, m = m0 + mi;
  const int c0 = s * CSL;

  float Gt[8][4], Yt[8];
#pragma unroll
  for (int i = 0; i < 8; ++i) {
    Yt[i] = 0.f;
#pragma unroll
    for (int j = 0; j < 4; ++j) Gt[i][j] = 0.f;
  }

  float4 st[2];
  stage_load512(st, x, c0, m0, t);
  stage_write_t(st, Sm, t);
  for (int ch = 0; ch < NCH; ++ch) {
    if (ch + 1 < NCH) stage_load512(st, x, c0 + (ch + 1) * CC, m0, t);
    __syncthreads();
    const float* cur = Sm + (ch & 1) * SLABF;
#pragma unroll
    for (int cc = 0; cc < CC; ++cc) {
      const int c = c0 + ch * CC + cc;
      const float* v = cur + cc * SLABC + mi * LDP;
      float4 ra = *reinterpret_cast<const float4*>(v + r0);       // rows r0..r0+3
      float4 rb = *reinterpret_cast<const float4*>(v + r0 + 4);   // rows r0+4..r0+7
      float4 cb = *reinterpret_cast<const float4*>(v + b0);       // cols b0..b0+3
      const float w = omega[c * 8 + bj];                          // L1-resident
      float rv[8] = {ra.x, ra.y, ra.z, ra.w, rb.x, rb.y, rb.z, rb.w};
#pragma unroll
      for (int i = 0; i < 8; ++i) {
        Gt[i][0] = fmaf(rv[i], cb.x, Gt[i][0]);
        Gt[i][1] = fmaf(rv[i], cb.y, Gt[i][1]);
        Gt[i][2] = fmaf(rv[i], cb.z, Gt[i][2]);
        Gt[i][3] = fmaf(rv[i], cb.w, Gt[i][3]);
        Yt[i]    = fmaf(rv[i], w,    Yt[i]);
      }
    }
    if (ch + 1 < NCH) stage_write_t(st, Sm + ((ch + 1) & 1) * SLABF, t);
  }

  // record-major store: G tile rows as float4; Y scalar (q = bj)
  float4* rec = reinterpret_cast<float4*>(Gp + ((size_t)s * HW + m) * GK);
#pragma unroll
  for (int i = 0; i < 8; ++i)
    rec[(r0 + i) * 8 + bj] = make_float4(Gt[i][0], Gt[i][1], Gt[i][2], Gt[i][3]);
  float* recf = Gp + ((size_t)s * HW + m) * GK + 1024;
#pragma unroll
  for (int i = 0; i < 8; ++i)
    recf[(r0 + i) * 8 + bj] = Yt[i];
}

// ============ K1b: reduce slices -> CholQR2 chain -> Q2 (32x8 per m) ============
__global__ __launch_bounds__(256) void tsvd_k1b(const float* __restrict__ Gp,
                                                float* __restrict__ Qws) {
  __shared__ float Sm[SMEMF];
  const int t = threadIdx.x;
  const int r = t & 31, mi = t >> 5;            // 8 m per block, thread owns row r
  const int m0 = blockIdx.x * 8, m = m0 + mi;

  float G0[32], Y0[8];
#pragma unroll
  for (int b = 0; b < 32; ++b) G0[b] = 0.f;
#pragma unroll
  for (int q = 0; q < 8; ++q) Y0[q] = 0.f;
#pragma unroll
  for (int s = 0; s < NS; ++s) {
    const float4* rec = reinterpret_cast<const float4*>(Gp + ((size_t)s * HW + m) * GK);
#pragma unroll
    for (int k = 0; k < 8; ++k) {               // 8 dense global_load_dwordx4
      float4 v = rec[r * 8 + k];
      G0[4 * k + 0] += v.x;
      G0[4 * k + 1] += v.y;
      G0[4 * k + 2] += v.z;
      G0[4 * k + 3] += v.w;
    }
    float4 y0 = rec[256 + r * 2 + 0];
    float4 y1 = rec[256 + r * 2 + 1];
    Y0[0] += y0.x; Y0[1] += y0.y; Y0[2] += y0.z; Y0[3] += y0.w;
    Y0[4] += y1.x; Y0[5] += y1.y; Y0[6] += y1.z; Y0[7] += y1.w;
  }

#pragma unroll
  for (int q = 0; q < 8; ++q) YT_(mi, r, q) = Y0[q];
  __syncthreads();

#pragma unroll
  for (int it = 0; it < 3; ++it) {
    cholqr32(Sm, mi, r);        // CholQR2: orthonormal basis of span(Y)
    cholqr32(Sm, mi, r);
    if (it < 2) {
      // U = G*Q -> WT
      float u[8];
#pragma unroll
      for (int q = 0; q < 8; ++q) {
        float a = 0.f;
#pragma unroll
        for (int b = 0; b < 32; ++b) a = fmaf(G0[b], YT_(mi, b, q), a);
        u[q] = a;
      }
#pragma unroll
      for (int q = 0; q < 8; ++q) WT_(mi, r, q) = u[q];
      __syncthreads();
      // T = Q^T G Q -> SS
#pragma unroll
      for (int e = 0; e < 2; ++e) {
        int idx = r + e * 32, i2 = idx >> 3, j2 = idx & 7;
        float a = 0.f;
#pragma unroll
        for (int b = 0; b < 32; ++b) a = fmaf(YT_(mi, b, i2), WT_(mi, b, j2), a);
        SS_(mi, idx) = a;
      }
      __syncthreads();
      // W = Q R^{-1} -> WT   (implicit qr(A*Q))
      {
        float Rl[36];
        chol8(Sm, mi, Rl);
        trsm1row(Sm, Sm + 4240, mi, r, Rl);
      }
      __syncthreads();
      // Y_next = G*W -> YT
#pragma unroll
      for (int q = 0; q < 8; ++q) {
        float a = 0.f;
#pragma unroll
        for (int b = 0; b < 32; ++b) a = fmaf(G0[b], WT_(mi, b, q), a);
        u[q] = a;
      }
#pragma unroll
      for (int q = 0; q < 8; ++q) YT_(mi, r, q) = u[q];
      __syncthreads();
    }
  }

  // store Q2 row r: Qws[m*256 + r*8 + q]
  float q0[8];
#pragma unroll
  for (int q = 0; q < 8; ++q) q0[q] = YT_(mi, r, q);
  float4* qrec = reinterpret_cast<float4*>(Qws + (size_t)m * 256);
  qrec[r * 2 + 0] = make_float4(q0[0], q0[1], q0[2], q0[3]);
  qrec[r * 2 + 1] = make_float4(q0[4], q0[5], q0[6], q0[7]);
}

// ============ K2: P = A Q2 (stage1), y = P Q2^T (stage2), per m ============
// thread = (mi, g); stage1 role: (cj = g&7, qd = g>>3 -> q pair); stage2 role: r = g
__global__ __launch_bounds__(512, 4) void tsvd_k2(const float* __restrict__ x,
                                                  const float* __restrict__ Qws,
                                                  float* __restrict__ y) {
  __shared__ float Sm2[2 * SLABF + TM * PST];
  float* Pl = Sm2 + 2 * SLABF;
  const int t = threadIdx.x;
  const int mi = t & 15, g = t >> 4;
  const int cj = g & 7, qd = g >> 3;
  const int r = g;
  const int bid = blockIdx.x;
  const int mt = bid % 196, cq = bid / 196;     // 196 m-tiles x 8 c-slices of 32
  const int m0 = mt * TM, m = m0 + mi;
  const int cbase = cq * 32;

  // Q2 columns (2qd, 2qd+1) for stage1; Q2 row r for stage2
  const float* qrec = Qws + (size_t)m * 256;
  float Qc0[32], Qc1[32];
#pragma unroll
  for (int b = 0; b < 32; ++b) {
    float2 v = reinterpret_cast<const float2*>(qrec)[b * 4 + qd];
    Qc0[b] = v.x; Qc1[b] = v.y;
  }
  float Qr[8];
  {
    float4 a = reinterpret_cast<const float4*>(qrec)[r * 2 + 0];
    float4 b4 = reinterpret_cast<const float4*>(qrec)[r * 2 + 1];
    Qr[0] = a.x; Qr[1] = a.y; Qr[2] = a.z; Qr[3] = a.w;
    Qr[4] = b4.x; Qr[5] = b4.y; Qr[6] = b4.z; Qr[7] = b4.w;
  }

  float4 st[2];
  stage_load512(st, x, cbase, m0, t);
  stage_write_t(st, Sm2, t);
  for (int ch = 0; ch < 4; ++ch) {
    if (ch + 1 < 4) stage_load512(st, x, cbase + (ch + 1) * CC, m0, t);
    __syncthreads();                      // slab ready; P free (prev stage2 done)
    const float* cur = Sm2 + (ch & 1) * SLABF;
    // ---- stage1: P[cj][2qd+e] = sum_b x[b][c] * Q2[b][2qd+e] ----
    {
      const float* v = cur + cj * SLABC + mi * LDP;
      float p0 = 0.f, p1 = 0.f;
#pragma unroll
      for (int k = 0; k < 8; ++k) {
        float4 xb = *reinterpret_cast<const float4*>(v + 4 * k);
        p0 = fmaf(xb.x, Qc0[4 * k + 0], p0);
        p0 = fmaf(xb.y, Qc0[4 * k + 1], p0);
        p0 = fmaf(xb.z, Qc0[4 * k + 2], p0);
        p0 = fmaf(xb.w, Qc0[4 * k + 3], p0);
        p1 = fmaf(xb.x, Qc1[4 * k + 0], p1);
        p1 = fmaf(xb.y, Qc1[4 * k + 1], p1);
        p1 = fmaf(xb.z, Qc1[4 * k + 2], p1);
        p1 = fmaf(xb.w, Qc1[4 * k + 3], p1);
      }
      *reinterpret_cast<float2*>(Pl + mi * PST + cj * 8 + 2 * qd) = make_float2(p0, p1);
    }
    if (ch + 1 < 4) stage_write_t(st, Sm2 + ((ch + 1) & 1) * SLABF, t);
    __syncthreads();                      // P visible
    // ---- stage2: y[r][c] = sum_q Qr[q] * P[c][q], 8 c's ----
    const float* Pm = Pl + mi * PST;
#pragma unroll
    for (int c2 = 0; c2 < 8; ++c2) {
      float4 pa = *reinterpret_cast<const float4*>(Pm + c2 * 8);
      float4 pb = *reinterpret_cast<const float4*>(Pm + c2 * 8 + 4);
      float a = 0.f;
      a = fmaf(Qr[0], pa.x, a);
      a = fmaf(Qr[1], pa.y, a);
      a = fmaf(Qr[2], pa.z, a);
      a = fmaf(Qr[3], pa.w, a);
      a = fmaf(Qr[4], pb.x, a);
      a = fmaf(Qr[5], pb.y, a);
      a = fmaf(Qr[6], pb.z, a);
      a = fmaf(Qr[7], pb.w, a);
      const int c = cbase + ch * CC + c2;
      y[((size_t)r * NC + c) * HW + m] = a;
    }
  }
}

extern "C" void kernel_launch(void* const* d_in, const int* in_sizes, int n_in,
                              void* d_out, int out_size, void* d_ws, size_t ws_size,
                              hipStream_t stream) {
  const float* x     = (const float*)d_in[0];   // 32*256*3136 fp32
  const float* omega = (const float*)d_in[1];   // 256*8 fp32
  float* y   = (float*)d_out;                   // 32*256*3136 fp32
  float* Qws = (float*)d_ws;                    // 3136*256*4 = 3.2 MB
  // Partial Gram scratch in d_out: 4*3136*1280*4B = 64.2 MB < 102.8 MB;
  // consumed by k1b, then k2 overwrites all of d_out with y.
  float* Gp  = (float*)d_out;

  tsvd_k1a<<<196 * NS, 512, 0, stream>>>(x, omega, Gp);
  tsvd_k1b<<<HW / 8, 256, 0, stream>>>(Gp, Qws);
  tsvd_k2<<<196 * 8, 512, 0, stream>>>(x, Qws, y);
}